// Round 8
// baseline (1380.694 us; speedup 1.0000x reference)
//
#include <hip/hip_runtime.h>

// CRF Viterbi decode: B=64, T=1024, K=256.
// emissions [B,T,K] f32, transitions [K,K] f32 (prev->next). out [B,T] f32 tags.
//
// Two-resource model (fits r0-r7): step time = max(LDS-pipe cyc, VALU-issue
// cyc) + stalls.  LDS: ds_read_b128 ~12 cyc/CU (broadcast NOT discounted),
// b32 ~5.8.  r0/r7 = LDS-bound at 1930 (128 broadcast b128: 16 waves x 8,
// because TWO waves duplicate each prev-group's state reads).  r7 (pk_add)
// cut VALU 1720->1184 with zero time change, proving LDS-bound.
//
// r8: 512 threads, 8 waves, wave w = prev group w (NO duplication):
//   - wave reads its group's 32 state floats once: 8 broadcast b128; total
//     64 b128/step (was 128) -> LDS ~1160 cyc/step.
//   - each lane handles 4 columns (l, l+64, l+128, l+192); each float4
//     state chunk reused across the 4 columns in registers (r7's pk_add +
//     max3 shape per column, bit-exact).
//   - emissions only touched by reducer threads (tid<256), whose column
//     IS tid (64*(tid>>6)+(tid&63)) -> no runtime-indexed reg arrays.
//   - reducer / deferred-gid / M,state writes VERBATIM r0 (waves 0-3,
//     one per SIMD).  VALU ~660 cyc/SIMD/step -> stays hidden under LDS.
// Values bit-identical -> bp_gid / seg_maps / compose / emit untouched.
//
// Path A: forward -> bp_gid -> seg_maps -> compose -> emit.
// Path B: forward(no gid) + bp_matrix full scan + chase.  Path C: zero.

#define CRF_B 64
#define CRF_T 1024
#define CRF_K 256
#define NSEG  16
#define SEGLEN 64

#define FG 8
#define FP 32

// ---------------------------------------------------------------------------
// Forward
// ---------------------------------------------------------------------------

typedef float f32x2 __attribute__((ext_vector_type(2)));

__global__ __launch_bounds__(512, 2) void crf_forward_states(
    const float* __restrict__ em, const float* __restrict__ trans,
    float* __restrict__ M, unsigned char* __restrict__ gidp)
{
    const int b   = blockIdx.x;
    const int tid = threadIdx.x;
    const int g   = tid >> 6;      // wave = prev group 0..7
    const int l   = tid & 63;      // lane -> columns l, l+64, l+128, l+192

    __shared__ __align__(16) float s_state[CRF_K];
    __shared__ float s_partial[FG][CRF_K];

    const int pbase = g * FP;

    // trans fragments: t01/t23[ci][k] = trans[pbase+4k .. +3][l + 64*ci]
    // as f32x2 prev-pairs (VOP3P-ready).  All indices compile-time after
    // unroll -> register-resident (AGPR-eligible like r0/r7).
    f32x2 t01[4][8], t23[4][8];
#pragma unroll
    for (int ci = 0; ci < 4; ++ci) {
        const int col = l + 64 * ci;
#pragma unroll
        for (int k = 0; k < 8; ++k) {
            const int p = pbase + 4 * k;
            t01[ci][k].x = trans[(size_t)p * CRF_K + col];
            t01[ci][k].y = trans[(size_t)(p + 1) * CRF_K + col];
            t23[ci][k].x = trans[(size_t)(p + 2) * CRF_K + col];
            t23[ci][k].y = trans[(size_t)(p + 3) * CRF_K + col];
        }
    }

    const float* emb = em + (size_t)b * CRF_T * CRF_K;
    if (tid < CRF_K) s_state[tid] = emb[tid];          // state[0] = em[0]
    float e_cur = 0.0f;
    if (tid < CRF_K) e_cur = emb[CRF_K + tid];         // emission for t = 1
    __syncthreads();

    // deferred-gid state (reducer threads only; saved across the barrier)
    float sp0 = 0, sp1 = 0, sp2 = 0, sp3 = 0;
    float sp4 = 0, sp5 = 0, sp6 = 0, sp7 = 0;
    float sbv = 0;

    for (int t = 1; t < CRF_T; ++t) {
        // deferred gid store for step t-1 (overlaps all waves' chunk compute)
        if (gidp && tid < CRF_K && t > 1) {
            int bg = 7;
            if (sp6 == sbv) bg = 6;
            if (sp5 == sbv) bg = 5;
            if (sp4 == sbv) bg = 4;
            if (sp3 == sbv) bg = 3;
            if (sp2 == sbv) bg = 2;
            if (sp1 == sbv) bg = 1;
            if (sp0 == sbv) bg = 0;
            int g1 = __shfl_down(bg, 1, 64);
            if ((tid & 1) == 0)
                gidp[((size_t)(t - 1) * CRF_B + b) * 128 + (tid >> 1)] =
                    (unsigned char)(bg | (g1 << 4));
        }

        float e_next = 0.0f;
        if (tid < CRF_K && t + 1 < CRF_T)
            e_next = emb[(t + 1) * CRF_K + tid];

        // ---- chunk compute: 8 broadcast b128 reads, each reused x4 cols ----
        const float4* sp = (const float4*)(s_state + pbase);
        float m0 = -INFINITY, m1 = -INFINITY;
        float m2 = -INFINITY, m3 = -INFINITY;
#pragma unroll
        for (int k = 0; k < 8; ++k) {
            const float4 sv = sp[k];
            f32x2 s01; s01.x = sv.x; s01.y = sv.y;
            f32x2 s23; s23.x = sv.z; s23.y = sv.w;
            {   // col l
                f32x2 a01 = s01 + t01[0][k];
                f32x2 a23 = s23 + t23[0][k];
                float r0 = fmaxf(fmaxf(a01.x, a01.y), a23.x);
                m0 = fmaxf(fmaxf(r0, a23.y), m0);
            }
            {   // col l+64
                f32x2 a01 = s01 + t01[1][k];
                f32x2 a23 = s23 + t23[1][k];
                float r0 = fmaxf(fmaxf(a01.x, a01.y), a23.x);
                m1 = fmaxf(fmaxf(r0, a23.y), m1);
            }
            {   // col l+128
                f32x2 a01 = s01 + t01[2][k];
                f32x2 a23 = s23 + t23[2][k];
                float r0 = fmaxf(fmaxf(a01.x, a01.y), a23.x);
                m2 = fmaxf(fmaxf(r0, a23.y), m2);
            }
            {   // col l+192
                f32x2 a01 = s01 + t01[3][k];
                f32x2 a23 = s23 + t23[3][k];
                float r0 = fmaxf(fmaxf(a01.x, a01.y), a23.x);
                m3 = fmaxf(fmaxf(r0, a23.y), m3);
            }
        }

        s_partial[g][l]       = m0;
        s_partial[g][l + 64]  = m1;
        s_partial[g][l + 128] = m2;
        s_partial[g][l + 192] = m3;
        __syncthreads();

        if (tid < CRF_K) {      // reducer: verbatim r0 (waves 0-3)
            float p0 = s_partial[0][tid], p1 = s_partial[1][tid];
            float p2 = s_partial[2][tid], p3 = s_partial[3][tid];
            float p4 = s_partial[4][tid], p5 = s_partial[5][tid];
            float p6 = s_partial[6][tid], p7 = s_partial[7][tid];
            float q0 = fmaxf(fmaxf(p0, p1), p2);    // max3
            float q1 = fmaxf(fmaxf(p3, p4), p5);    // max3
            float bv = fmaxf(fmaxf(fmaxf(q0, q1), p6), p7);
            s_state[tid] = bv + e_cur;
            M[((size_t)t * CRF_B + b) * CRF_K + tid] = bv;   // PRE-emission
            sp0 = p0; sp1 = p1; sp2 = p2; sp3 = p3;
            sp4 = p4; sp5 = p5; sp6 = p6; sp7 = p7; sbv = bv;
        }
        __syncthreads();
        e_cur = e_next;
    }

    // flush gid for the final row (t = CRF_T-1)
    if (gidp && tid < CRF_K) {
        int bg = 7;
        if (sp6 == sbv) bg = 6;
        if (sp5 == sbv) bg = 5;
        if (sp4 == sbv) bg = 4;
        if (sp3 == sbv) bg = 3;
        if (sp2 == sbv) bg = 2;
        if (sp1 == sbv) bg = 1;
        if (sp0 == sbv) bg = 0;
        int g1 = __shfl_down(bg, 1, 64);
        if ((tid & 1) == 0)
            gidp[((size_t)(CRF_T - 1) * CRF_B + b) * 128 + (tid >> 1)] =
                (unsigned char)(bg | (g1 << 4));
    }
}

// ---------------------------------------------------------------------------
// bp via gid: 512 blocks (b x cg4 x ts2) x 256 thr (4 waves, t1 stride 4).
// 64KB transposed trans tile; gid byte for next iteration prefetched.
// ---------------------------------------------------------------------------

#define BPG_CHUNK(j) { \
    float4 mm = M4[j]; float4 ee = E4[j]; \
    float s0 = mm.x + ee.x, s1 = mm.y + ee.y; \
    float s2 = mm.z + ee.z, s3 = mm.w + ee.w; \
    float t0v = s_tile[base + 4*(j) + 0][lane]; \
    float t1v = s_tile[base + 4*(j) + 1][lane]; \
    float t2v = s_tile[base + 4*(j) + 2][lane]; \
    float t3v = s_tile[base + 4*(j) + 3][lane]; \
    float v0 = s0 + t0v; if (v0 > best) { best = v0; arg = base + 4*(j); } \
    float v1 = s1 + t1v; if (v1 > best) { best = v1; arg = base + 4*(j) + 1; } \
    float v2 = s2 + t2v; if (v2 > best) { best = v2; arg = base + 4*(j) + 2; } \
    float v3 = s3 + t3v; if (v3 > best) { best = v3; arg = base + 4*(j) + 3; } }

#define BPG_CHUNK0(j) { \
    float4 ee = E4[j]; \
    float t0v = s_tile[base + 4*(j) + 0][lane]; \
    float t1v = s_tile[base + 4*(j) + 1][lane]; \
    float t2v = s_tile[base + 4*(j) + 2][lane]; \
    float t3v = s_tile[base + 4*(j) + 3][lane]; \
    float v0 = ee.x + t0v; if (v0 > best) { best = v0; arg = base + 4*(j); } \
    float v1 = ee.y + t1v; if (v1 > best) { best = v1; arg = base + 4*(j) + 1; } \
    float v2 = ee.z + t2v; if (v2 > best) { best = v2; arg = base + 4*(j) + 2; } \
    float v3 = ee.w + t3v; if (v3 > best) { best = v3; arg = base + 4*(j) + 3; } }

__global__ __launch_bounds__(256) void crf_bp_gid(
    const float* __restrict__ M, const float* __restrict__ em,
    const float* __restrict__ trans, const unsigned char* __restrict__ gidp,
    unsigned char* __restrict__ bp)
{
    const int b    = blockIdx.x >> 3;
    const int cg   = (blockIdx.x >> 1) & 3;
    const int ts   = blockIdx.x & 1;
    const int tid  = threadIdx.x;
    const int lane = tid & 63;
    const int w    = tid >> 6;      // wave 0..3

    __shared__ float s_tile[CRF_K][64];   // 64 KB: s_tile[prev][col]

    const int k0 = cg * 64;
    for (int idx = tid; idx < CRF_K * 64; idx += 256) {
        const int p = idx >> 6, cc = idx & 63;
        s_tile[p][cc] = trans[(size_t)p * CRF_K + k0 + cc];
    }
    __syncthreads();

    const int t_lo = ts * 512;
    const int t_hi = ts ? (CRF_T - 1) : 512;
    const int half = (k0 >> 1) + (lane >> 1);
    const int odd  = lane & 1;

    int t1 = t_lo + w;
    if (t1 >= t_hi) return;
    unsigned char gb = gidp[((size_t)(t1 + 1) * CRF_B + b) * 128 + half];

    for (; t1 < t_hi; t1 += 4) {
        const int tn = t1 + 4;
        unsigned char gb_next = 0;
        if (tn < t_hi)                         // prefetch next gid byte
            gb_next = gidp[((size_t)(tn + 1) * CRF_B + b) * 128 + half];

        const int g    = odd ? ((gb >> 4) & 7) : (gb & 7);
        const int base = g << 5;
        const float4* E4 =
            (const float4*)(em + ((size_t)b * CRF_T + t1) * CRF_K + base);
        float best = -INFINITY; int arg = base;
        if (t1 == 0) {                         // state[0] = em[0]
            BPG_CHUNK0(0) BPG_CHUNK0(1) BPG_CHUNK0(2) BPG_CHUNK0(3)
            BPG_CHUNK0(4) BPG_CHUNK0(5) BPG_CHUNK0(6) BPG_CHUNK0(7)
        } else {
            const float4* M4 =
                (const float4*)(M + ((size_t)t1 * CRF_B + b) * CRF_K + base);
            BPG_CHUNK(0) BPG_CHUNK(1) BPG_CHUNK(2) BPG_CHUNK(3)
            BPG_CHUNK(4) BPG_CHUNK(5) BPG_CHUNK(6) BPG_CHUNK(7)
        }
        bp[((size_t)b * (CRF_T - 1) + t1) * CRF_K + k0 + lane] =
            (unsigned char)arg;
        gb = gb_next;
    }
}

// ---------------------------------------------------------------------------
// Fallback-B backpointers: full-scan bp_matrix (proven), state = M+em.
// ---------------------------------------------------------------------------

__global__ __launch_bounds__(1024, 2) void crf_bp_matrix(
    const float* __restrict__ M, const float* __restrict__ em,
    const float* __restrict__ trans, unsigned char* __restrict__ bp)
{
    const int b   = blockIdx.x >> 4;
    const int seg = blockIdx.x & 15;
    const int tid = threadIdx.x;
    const int g   = tid >> 8;      // 0..3
    const int k   = tid & 255;

    __shared__ __align__(16) float s_row[CRF_K];
    __shared__ float s_pv[4][CRF_K];
    __shared__ int   s_pi[4][CRF_K];

    const int pbase = g * 64;
    float4 tr[16];
#pragma unroll
    for (int i = 0; i < 16; ++i) {
        const int p = pbase + 4 * i;
        tr[i].x = trans[(p + 0) * CRF_K + k];
        tr[i].y = trans[(p + 1) * CRF_K + k];
        tr[i].z = trans[(p + 2) * CRF_K + k];
        tr[i].w = trans[(p + 3) * CRF_K + k];
    }

    const int t_lo = seg * SEGLEN;
    const int t_hi = min(t_lo + SEGLEN, CRF_T - 1);
    unsigned char* bpb = bp + (size_t)b * (CRF_T - 1) * CRF_K;

    for (int t1 = t_lo; t1 < t_hi; ++t1) {
        if (tid < CRF_K) {
            float ev = em[((size_t)b * CRF_T + t1) * CRF_K + tid];
            float sv = ev;
            if (t1 > 0) sv = M[((size_t)t1 * CRF_B + b) * CRF_K + tid] + ev;
            s_row[tid] = sv;
        }
        __syncthreads();

        float best = -INFINITY;
        int   arg  = pbase;
        const float4* spp = (const float4*)(s_row + pbase);
#pragma unroll
        for (int i = 0; i < 16; ++i) {
            float4 st = spp[i];
            const int p = pbase + 4 * i;
            float s0 = st.x + tr[i].x;
            float s1 = st.y + tr[i].y;
            float s2 = st.z + tr[i].z;
            float s3 = st.w + tr[i].w;
            if (s0 > best) { best = s0; arg = p; }
            if (s1 > best) { best = s1; arg = p + 1; }
            if (s2 > best) { best = s2; arg = p + 2; }
            if (s3 > best) { best = s3; arg = p + 3; }
        }
        s_pv[g][k] = best;
        s_pi[g][k] = arg;
        __syncthreads();
        if (tid < CRF_K) {
            float bv = s_pv[0][tid];
            int   ba = s_pi[0][tid];
#pragma unroll
            for (int j = 1; j < 4; ++j) {
                float v = s_pv[j][tid];
                if (v > bv) { bv = v; ba = s_pi[j][tid]; }
            }
            bpb[(size_t)t1 * CRF_K + tid] = (unsigned char)ba;
        }
        __syncthreads();
    }
}

// ---------------------------------------------------------------------------
// Segmented chase (proven): seg_maps -> compose -> emit.
// ---------------------------------------------------------------------------

__global__ __launch_bounds__(256) void crf_seg_maps(
    const unsigned char* __restrict__ bp, unsigned char* __restrict__ maps)
{
    const int b   = blockIdx.x >> 4;
    const int s   = blockIdx.x & 15;
    const int tid = threadIdx.x;
    const int rows = (s == NSEG - 1) ? SEGLEN - 1 : SEGLEN;
    const int r0   = s * SEGLEN;

    __shared__ unsigned char lbp[SEGLEN][CRF_K];   // 16 KB

    const unsigned char* bpb = bp + (size_t)b * (CRF_T - 1) * CRF_K;
    const int nw = rows * 64;
    for (int w = tid; w < nw; w += 256) {
        const int r = w >> 6, cc = w & 63;
        ((unsigned int*)lbp[r])[cc] =
            ((const unsigned int*)(bpb + (size_t)(r0 + r) * CRF_K))[cc];
    }
    __syncthreads();

    int tag = tid;
    for (int j = rows - 1; j >= 0; --j) tag = lbp[j][tag];
    maps[((size_t)b * NSEG + s) * CRF_K + tid] = (unsigned char)tag;
}

__global__ __launch_bounds__(256) void crf_compose(
    const float* __restrict__ M, const float* __restrict__ em,
    const unsigned char* __restrict__ maps,
    int* __restrict__ exits, float* __restrict__ out)
{
    const int b   = blockIdx.x;
    const int tid = threadIdx.x;

    __shared__ float s_wv[4];
    __shared__ int   s_wi[4];

    float v = M[((size_t)(CRF_T - 1) * CRF_B + b) * CRF_K + tid]
            + em[((size_t)b * CRF_T + (CRF_T - 1)) * CRF_K + tid];
    int   i = tid;
#pragma unroll
    for (int off = 32; off >= 1; off >>= 1) {
        float ov = __shfl_xor(v, off, 64);
        int   oi = __shfl_xor(i, off, 64);
        if (ov > v || (ov == v && oi < i)) { v = ov; i = oi; }
    }
    const int lane = tid & 63, wv = tid >> 6;
    if (lane == 0) { s_wv[wv] = v; s_wi[wv] = i; }
    __syncthreads();
    if (tid == 0) {
        float bv = s_wv[0]; int bi = s_wi[0];
#pragma unroll
        for (int w = 1; w < 4; ++w)
            if (s_wv[w] > bv) { bv = s_wv[w]; bi = s_wi[w]; }
        out[(size_t)b * CRF_T + (CRF_T - 1)] = (float)bi;
        int E = bi;
        exits[b * NSEG + NSEG - 1] = E;
        const unsigned char* mb = maps + (size_t)b * NSEG * CRF_K;
        for (int s = NSEG - 1; s >= 1; --s) {
            E = mb[(size_t)s * CRF_K + E];
            exits[b * NSEG + s - 1] = E;
        }
    }
}

__global__ __launch_bounds__(256) void crf_emit(
    const unsigned char* __restrict__ bp, const int* __restrict__ exits,
    float* __restrict__ out)
{
    const int b   = blockIdx.x >> 4;
    const int s   = blockIdx.x & 15;
    const int tid = threadIdx.x;
    const int rows = (s == NSEG - 1) ? SEGLEN - 1 : SEGLEN;
    const int r0   = s * SEGLEN;

    __shared__ unsigned char lbp[SEGLEN][CRF_K];

    const unsigned char* bpb = bp + (size_t)b * (CRF_T - 1) * CRF_K;
    const int nw = rows * 64;
    for (int w = tid; w < nw; w += 256) {
        const int r = w >> 6, cc = w & 63;
        ((unsigned int*)lbp[r])[cc] =
            ((const unsigned int*)(bpb + (size_t)(r0 + r) * CRF_K))[cc];
    }
    __syncthreads();

    int tag = tid;
    const bool win = (tid == exits[b * NSEG + s]);
    for (int j = rows - 1; j >= 0; --j) {
        tag = lbp[j][tag];
        if (win) out[(size_t)b * CRF_T + r0 + j] = (float)tag;
    }
}

__global__ void crf_zero_out(float* __restrict__ out, int n)
{
    int i = blockIdx.x * blockDim.x + threadIdx.x;
    if (i < n) out[i] = 0.0f;
}

// ---------------------------------------------------------------------------

extern "C" void kernel_launch(void* const* d_in, const int* in_sizes, int n_in,
                              void* d_out, int out_size, void* d_ws, size_t ws_size,
                              hipStream_t stream) {
    (void)in_sizes; (void)n_in;
    const float* em    = (const float*)d_in[0];   // [B,T,K]
    const float* trans = (const float*)d_in[1];   // [K,K]
    float* out = (float*)d_out;                   // [B,T]

    const size_t M_bytes     = (size_t)CRF_T * CRF_B * CRF_K * sizeof(float); // 64 MB
    const size_t gid_bytes   = (size_t)CRF_T * CRF_B * 128;                   // 8.4 MB
    const size_t bp_bytes    = (size_t)CRF_B * (CRF_T - 1) * CRF_K;           // 16.75 MB
    const size_t maps_bytes  = (size_t)CRF_B * NSEG * CRF_K;                  // 256 KB
    const size_t exits_bytes = (size_t)CRF_B * NSEG * sizeof(int);            // 4 KB

    char* w = (char*)d_ws;
    if (ws_size >= M_bytes + gid_bytes + bp_bytes + maps_bytes + exits_bytes) {
        float*         M     = (float*)w;            w += M_bytes;
        unsigned char* gidp  = (unsigned char*)w;    w += gid_bytes;
        unsigned char* bp    = (unsigned char*)w;    w += bp_bytes;
        unsigned char* maps  = (unsigned char*)w;    w += maps_bytes;
        int*           exits = (int*)w;

        crf_forward_states<<<CRF_B, 512, 0, stream>>>(em, trans, M, gidp);
        crf_bp_gid<<<CRF_B * 8, 256, 0, stream>>>(M, em, trans, gidp, bp);
        crf_seg_maps<<<CRF_B * NSEG, 256, 0, stream>>>(bp, maps);
        crf_compose<<<CRF_B, 256, 0, stream>>>(M, em, maps, exits, out);
        crf_emit<<<CRF_B * NSEG, 256, 0, stream>>>(bp, exits, out);
    } else if (ws_size >= M_bytes + bp_bytes + maps_bytes + exits_bytes) {
        float*         M     = (float*)w;            w += M_bytes;
        unsigned char* bp    = (unsigned char*)w;    w += bp_bytes;
        unsigned char* maps  = (unsigned char*)w;    w += maps_bytes;
        int*           exits = (int*)w;

        crf_forward_states<<<CRF_B, 512, 0, stream>>>(em, trans, M, nullptr);
        crf_bp_matrix<<<CRF_B * NSEG, 1024, 0, stream>>>(M, em, trans, bp);
        crf_seg_maps<<<CRF_B * NSEG, 256, 0, stream>>>(bp, maps);
        crf_compose<<<CRF_B, 256, 0, stream>>>(M, em, maps, exits, out);
        crf_emit<<<CRF_B * NSEG, 256, 0, stream>>>(bp, exits, out);
    } else {
        crf_zero_out<<<(out_size + 255) / 256, 256, 0, stream>>>(out, out_size);
    }
}